// Round 8
// baseline (256.323 us; speedup 1.0000x reference)
//
#include <hip/hip_runtime.h>
#include <hip/hip_bf16.h>
#include <stdint.h>

// Problem constants
#define BB     8
#define CC     128
#define HW     9216      // 96*96
#define NHEAD  8
#define HD     64
#define NCH    16        // gram n-chunks
#define CHUNK  576       // HW/NCH
#define KPAD   68        // LDS row pad (px): 136B = 34 banks -> max 4-way conflict

typedef __hip_bfloat16 bf16;
using frag16 = __attribute__((ext_vector_type(8))) short;  // 8 bf16 (4 VGPRs)
using f32x4  = __attribute__((ext_vector_type(4))) float;

__device__ __forceinline__ float b2f(bf16 v) { return __bfloat162float(v); }
__device__ __forceinline__ bf16  f2b(float v) { return __float2bfloat16(v); }

__device__ __forceinline__ float us2f(unsigned short u) {
  union { unsigned int i; float f; } c; c.i = ((unsigned int)u) << 16; return c.f;
}

__device__ __forceinline__ unsigned int pack2(float a, float b) {
  union { __hip_bfloat162 h2; unsigned int u; } c;
  c.h2 = __float22bfloat162_rn(make_float2(a, b));   // v_cvt_pk_bf16_f32
  return c.u;
}

// LDS frag read from 8B-aligned address (rows are 136B-strided)
__device__ __forceinline__ frag16 ldsfrag(const unsigned short* p) {
  uint2 lo = *(const uint2*)p;
  uint2 hi = *(const uint2*)(p + 4);
  union { unsigned int u[4]; frag16 f; } c;
  c.u[0] = lo.x; c.u[1] = lo.y; c.u[2] = hi.x; c.u[3] = hi.y;
  return c.f;
}
// LDS 16B store as two 8B stores (8B-aligned dst)
__device__ __forceinline__ void ldsst(unsigned short* p, uint4 v) {
  *(uint2*)p = make_uint2(v.x, v.y);
  *(uint2*)(p + 4) = make_uint2(v.z, v.w);
}

// ---------------------------------------------------------------- K1: qkv depthwise conv + q/k norms
// block = (b, c). NO LDS staging: x plane read directly from global; the 3.75x
// re-read is served by L1 (live window ~15 rows ~6KB << 32KB L1). Removes the
// staging pass + barrier + 39.4KB LDS occupancy cap (-> 8 waves/SIMD possible,
// more TLP against the 221MB write stream). 8 px/thread units, edge-masked loads.
__global__ __launch_bounds__(256) void k1_qkv(
    const float* __restrict__ x, const float* __restrict__ wq,
    const float* __restrict__ bq,
    bf16* __restrict__ qg, bf16* __restrict__ kg, bf16* __restrict__ vg,
    float* __restrict__ qn2, float* __restrict__ kn2) {
  __shared__ float red[32];
  int tid = threadIdx.x;
  int wave = tid >> 6, lane = tid & 63;
  int b = blockIdx.x >> 7, c = blockIdx.x & 127;
  const float* xp = x + (size_t)(b * CC + c) * HW;

  int half = c >> 6, d = c & 63;
  int nidx[8];
  size_t basep[12];
#pragma unroll
  for (int j = 0; j < 12; ++j) {
    int e = j & 3;
    int h = e * 2 + half;
    int ni = (b * NHEAD + h) * HD + d;
    if (j < 8) nidx[j] = ni;
    basep[j] = (size_t)ni * HW;
  }
  const float* wrow = wq + c * 108;
  const float* brow = bq + c * 12;

  float ssq[8];
#pragma unroll
  for (int j = 0; j < 8; ++j) ssq[j] = 0.f;

#pragma unroll 1
  for (int it = 0; it < 5; ++it) {
    int u = it * 256 + tid;
    if (u < 1152) {
      int ly = u / 12;
      int x8 = (u - ly * 12) * 8;
      int p0 = ly * 96 + x8;
      float w10[3][10];
#pragma unroll
      for (int ky = 0; ky < 3; ++ky) {
        int gr = ly + ky - 1;
        bool ok = (unsigned)gr < 96u;
        const float* rp = xp + gr * 96 + x8;
        float4 M0 = ok ? *(const float4*)rp       : make_float4(0.f, 0.f, 0.f, 0.f);
        float4 M1 = ok ? *(const float4*)(rp + 4) : make_float4(0.f, 0.f, 0.f, 0.f);
        w10[ky][0] = (ok && x8 > 0)  ? rp[-1] : 0.f;
        w10[ky][1] = M0.x; w10[ky][2] = M0.y; w10[ky][3] = M0.z; w10[ky][4] = M0.w;
        w10[ky][5] = M1.x; w10[ky][6] = M1.y; w10[ky][7] = M1.z; w10[ky][8] = M1.w;
        w10[ky][9] = (ok && x8 < 88) ? rp[8]  : 0.f;
      }
#pragma unroll
      for (int j = 0; j < 12; ++j) {
        float bias = brow[j];
        float a[8];
#pragma unroll
        for (int p = 0; p < 8; ++p) a[p] = bias;
#pragma unroll
        for (int ky = 0; ky < 3; ++ky)
#pragma unroll
          for (int kx = 0; kx < 3; ++kx) {
            float w = wrow[j * 9 + ky * 3 + kx];
#pragma unroll
            for (int p = 0; p < 8; ++p)
              a[p] = fmaf(w, w10[ky][kx + p], a[p]);
          }
        uint4 st;
        st.x = pack2(a[0], a[1]); st.y = pack2(a[2], a[3]);
        st.z = pack2(a[4], a[5]); st.w = pack2(a[6], a[7]);
        if (j < 4)      *(uint4*)(qg + basep[j] + p0) = st;
        else if (j < 8) *(uint4*)(kg + basep[j] + p0) = st;
        else            *(uint4*)(vg + basep[j] + p0) = st;
        if (j < 8) {
          float s2 = 0.f;
#pragma unroll
          for (int p = 0; p < 8; ++p) s2 = fmaf(a[p], a[p], s2);
          ssq[j] += s2;
        }
      }
    }
  }
#pragma unroll
  for (int j = 0; j < 8; ++j) {
    float v = ssq[j];
#pragma unroll
    for (int off = 32; off > 0; off >>= 1) v += __shfl_down(v, off);
    if (lane == 0) red[wave * 8 + j] = v;
  }
  __syncthreads();
  if (tid < 8) {
    float s = red[tid] + red[8 + tid] + red[16 + tid] + red[24 + tid];
    if (tid < 4) qn2[nidx[tid]] = s;
    else         kn2[nidx[tid]] = s;
  }
}

// ---------------------------------------------------------------- K2a: gram partials via MFMA, LDS-staged
// block = (chunk, bh). Per BK=64 step: stage q[64][64] + k[64][64] into padded LDS
// (coalesced 8-row x 128B bursts, k shared by all 4 waves), double-buffered,
// reg-staged (issue loads -> compute -> ds_write -> barrier).
__global__ __launch_bounds__(256) void k2_gram(
    const bf16* __restrict__ qg, const bf16* __restrict__ kg,
    float* __restrict__ part) {
  __shared__ unsigned short sq[2][64 * KPAD];   // 17408 B
  __shared__ unsigned short sk[2][64 * KPAD];   // 17408 B
  int tid = threadIdx.x;
  int wave = tid >> 6;           // 0..3 -> d-tile
  int lane = tid & 63;
  int chunk = blockIdx.x;        // 0..15
  int bh = blockIdx.y;           // 0..63
  const size_t base = (size_t)bh * HD * HW;
  int n0 = chunk * CHUNK;

  // staging coords: thread covers (row, seg16B) and (row+32, seg16B)
  int srow = tid >> 3;           // 0..31
  int sseg = tid & 7;            // 0..7 (8px each)
  const bf16* qs0 = qg + base + (size_t)srow * HW + n0 + sseg * 8;
  const bf16* qs1 = qs0 + (size_t)32 * HW;
  const bf16* ks0 = kg + base + (size_t)srow * HW + n0 + sseg * 8;
  const bf16* ks1 = ks0 + (size_t)32 * HW;
  int d0 = srow * KPAD + sseg * 8;
  int d1 = (srow + 32) * KPAD + sseg * 8;

  int m = lane & 15;
  int k8 = lane >> 4;            // 0..3
  int arow = wave * 16 + m;

  f32x4 acc0 = {0.f, 0.f, 0.f, 0.f}, acc1 = acc0, acc2 = acc0, acc3 = acc0;

  // prologue: stage step 0
  uint4 rq0 = *(const uint4*)(qs0);
  uint4 rq1 = *(const uint4*)(qs1);
  uint4 rk0 = *(const uint4*)(ks0);
  uint4 rk1 = *(const uint4*)(ks1);
  ldsst(&sq[0][d0], rq0); ldsst(&sq[0][d1], rq1);
  ldsst(&sk[0][d0], rk0); ldsst(&sk[0][d1], rk1);
  __syncthreads();

#pragma unroll 1
  for (int s = 0; s < 9; ++s) {
    if (s < 8) {                       // issue next-step loads early (T14)
      int off = (s + 1) * 64;
      rq0 = *(const uint4*)(qs0 + off);
      rq1 = *(const uint4*)(qs1 + off);
      rk0 = *(const uint4*)(ks0 + off);
      rk1 = *(const uint4*)(ks1 + off);
    }
    const unsigned short* sqc = sq[s & 1];
    const unsigned short* skc = sk[s & 1];
#pragma unroll
    for (int kk = 0; kk < 2; ++kk) {
      int co = kk * 32 + k8 * 8;
      frag16 a  = ldsfrag(&sqc[arow * KPAD + co]);
      frag16 b0 = ldsfrag(&skc[(m +  0) * KPAD + co]);
      frag16 b1 = ldsfrag(&skc[(m + 16) * KPAD + co]);
      frag16 b2 = ldsfrag(&skc[(m + 32) * KPAD + co]);
      frag16 b3 = ldsfrag(&skc[(m + 48) * KPAD + co]);
      acc0 = __builtin_amdgcn_mfma_f32_16x16x32_bf16(a, b0, acc0, 0, 0, 0);
      acc1 = __builtin_amdgcn_mfma_f32_16x16x32_bf16(a, b1, acc1, 0, 0, 0);
      acc2 = __builtin_amdgcn_mfma_f32_16x16x32_bf16(a, b2, acc2, 0, 0, 0);
      acc3 = __builtin_amdgcn_mfma_f32_16x16x32_bf16(a, b3, acc3, 0, 0, 0);
    }
    if (s < 8) {                       // write next buffer; single barrier per step
      int nb = (s + 1) & 1;
      ldsst(&sq[nb][d0], rq0); ldsst(&sq[nb][d1], rq1);
      ldsst(&sk[nb][d0], rk0); ldsst(&sk[nb][d1], rk1);
      __syncthreads();
    }
  }

  // C/D layout: row(d) = (lane>>4)*4 + r, col(e) = lane&15
  float* po = part + (size_t)(bh * NCH + chunk) * 4096;
  int dr = wave * 16 + (lane >> 4) * 4;
  int e0 = lane & 15;
#pragma unroll
  for (int r = 0; r < 4; ++r) {
    po[(dr + r) * 64 +  0 + e0] = acc0[r];
    po[(dr + r) * 64 + 16 + e0] = acc1[r];
    po[(dr + r) * 64 + 32 + e0] = acc2[r];
    po[(dr + r) * 64 + 48 + e0] = acc3[r];
  }
}

// ---------------------------------------------------------------- K2b: reduce partials + normalize + softmax
__global__ __launch_bounds__(256) void k2_softmax(
    const float* __restrict__ part, bf16* __restrict__ ah, bf16* __restrict__ al,
    const float* __restrict__ qn2, const float* __restrict__ kn2,
    const float* __restrict__ t_f) {
  __shared__ float kns[64];
  int bh = blockIdx.x;
  int dq = blockIdx.y;
  int tid = threadIdx.x;
  if (tid < 64) kns[tid] = fmaxf(sqrtf(kn2[bh * 64 + tid]), 1e-12f);
  __syncthreads();
  int d  = dq * 16 + (tid >> 4);
  int e0 = (tid & 15) * 4;

  const float* pb = part + (size_t)bh * NCH * 4096 + d * 64 + e0;
  float4 s = make_float4(0.f, 0.f, 0.f, 0.f);
#pragma unroll
  for (int ch = 0; ch < NCH; ++ch) {
    float4 g = *(const float4*)&pb[ch * 4096];
    s.x += g.x; s.y += g.y; s.z += g.z; s.w += g.w;
  }
  float v[4] = {s.x, s.y, s.z, s.w};
  float sc = t_f[bh & 7] / fmaxf(sqrtf(qn2[bh * 64 + d]), 1e-12f);
  float m = -1e30f;
#pragma unroll
  for (int j = 0; j < 4; ++j) {
    v[j] = v[j] * sc / kns[e0 + j];
    m = fmaxf(m, v[j]);
  }
  m = fmaxf(m, __shfl_xor(m, 1));
  m = fmaxf(m, __shfl_xor(m, 2));
  m = fmaxf(m, __shfl_xor(m, 4));
  m = fmaxf(m, __shfl_xor(m, 8));
  float ssum = 0.f;
#pragma unroll
  for (int j = 0; j < 4; ++j) { v[j] = __expf(v[j] - m); ssum += v[j]; }
  ssum += __shfl_xor(ssum, 1);
  ssum += __shfl_xor(ssum, 2);
  ssum += __shfl_xor(ssum, 4);
  ssum += __shfl_xor(ssum, 8);
  float inv = 1.f / ssum;
  unsigned short hi16[4], lo16[4];
#pragma unroll
  for (int j = 0; j < 4; ++j) {
    float p = v[j] * inv;
    bf16 hi = f2b(p);
    float lo = p - b2f(hi);
    bf16 lov = f2b(lo);
    hi16[j] = *(unsigned short*)&hi;
    lo16[j] = *(unsigned short*)&lov;
  }
  const size_t base = (size_t)bh * 4096 + d * 64 + e0;
  *(ushort4*)(ah + base) = *(ushort4*)&hi16[0];
  *(ushort4*)(al + base) = *(ushort4*)&lo16[0];
}

// ---------------------------------------------------------------- K3: o = attn @ v via MFMA
__global__ __launch_bounds__(256) void k3_av(
    const bf16* __restrict__ ah, const bf16* __restrict__ al,
    const bf16* __restrict__ vg, bf16* __restrict__ og) {
  int tid = threadIdx.x;
  int wave = tid >> 6, lane = tid & 63;
  int chunk = blockIdx.x;   // 0..35 (256 pixels each)
  int bh = blockIdx.y;      // 0..63
  int b = bh >> 3, h = bh & 7;
  int n0 = chunk * 256;
  int m = lane & 15;
  int k8 = (lane >> 4) * 8;
  int nwbase = wave * 64;

  const bf16* ahp = ah + (size_t)bh * 4096;
  const bf16* alp = al + (size_t)bh * 4096;
  frag16 a_hi[4][2], a_lo[4][2];
#pragma unroll
  for (int dt = 0; dt < 4; ++dt)
#pragma unroll
    for (int kh = 0; kh < 2; ++kh) {
      a_hi[dt][kh] = *(const frag16*)(ahp + (dt * 16 + m) * 64 + kh * 32 + k8);
      a_lo[dt][kh] = *(const frag16*)(alp + (dt * 16 + m) * 64 + kh * 32 + k8);
    }

  const bf16* vb = vg + (size_t)bh * HD * HW + n0 + nwbase + m;
  frag16 bfr[4][2];
#pragma unroll
  for (int kh = 0; kh < 2; ++kh)
#pragma unroll
    for (int j = 0; j < 8; ++j) {
      const bf16* vp = vb + (size_t)(kh * 32 + k8 + j) * HW;
      bfr[0][kh][j] = *(const short*)(vp);
      bfr[1][kh][j] = *(const short*)(vp + 16);
      bfr[2][kh][j] = *(const short*)(vp + 32);
      bfr[3][kh][j] = *(const short*)(vp + 48);
    }

  f32x4 acc[4][4];
#pragma unroll
  for (int dt = 0; dt < 4; ++dt)
#pragma unroll
    for (int nt = 0; nt < 4; ++nt) acc[dt][nt] = {0.f, 0.f, 0.f, 0.f};

#pragma unroll
  for (int nt = 0; nt < 4; ++nt)
#pragma unroll
    for (int kh = 0; kh < 2; ++kh)
#pragma unroll
      for (int dt = 0; dt < 4; ++dt) {
        acc[dt][nt] = __builtin_amdgcn_mfma_f32_16x16x32_bf16(a_hi[dt][kh], bfr[nt][kh], acc[dt][nt], 0, 0, 0);
        acc[dt][nt] = __builtin_amdgcn_mfma_f32_16x16x32_bf16(a_lo[dt][kh], bfr[nt][kh], acc[dt][nt], 0, 0, 0);
      }

  int cc0 = (h & 1) * 256 + (h >> 1);
  bf16* ob = og + (size_t)b * 512 * HW;
  int q4 = (lane >> 4) * 4;
#pragma unroll
  for (int dt = 0; dt < 4; ++dt)
#pragma unroll
    for (int nt = 0; nt < 4; ++nt) {
      int n = n0 + nwbase + nt * 16 + m;
#pragma unroll
      for (int r = 0; r < 4; ++r) {
        int d = dt * 16 + q4 + r;
        ob[(size_t)(cc0 + d * 4) * HW + n] = f2b(acc[dt][nt][r]);
      }
    }
}

// ---------------------------------------------------------------- K4: fused grouped 3x3 conv (4 in-ch -> 1 out-ch)
__global__ __launch_bounds__(256) void k4_fuse(
    const bf16* __restrict__ og, const float* __restrict__ wf,
    const float* __restrict__ bfu, float* __restrict__ out) {
  __shared__ float lds[26 * 100 * 4];   // 41.6 KB
  int tid = threadIdx.x;
  int tile = blockIdx.x;                // 0..3
  int bc = blockIdx.y;                  // 0..1023
  int b = bc >> 7, c = bc & 127;
  int r0 = tile * 24 - 1;
  const float4 z4 = make_float4(0.f, 0.f, 0.f, 0.f);
  for (int i = tid; i < 52; i += 256) {
    int rr = i >> 1, cc = (i & 1) ? 98 : 1;
    *(float4*)&lds[(rr * 100 + cc) * 4] = z4;
  }
  if (r0 < 0)
    for (int i = tid; i < 96; i += 256) *(float4*)&lds[(0 * 100 + 2 + i) * 4] = z4;
  if (r0 + 25 >= 96)
    for (int i = tid; i < 96; i += 256) *(float4*)&lds[(25 * 100 + 2 + i) * 4] = z4;
  const bf16* op = og + (size_t)(b * 512 + c * 4) * HW;
  for (int i = tid; i < 26 * 24; i += 256) {
    int rr = i / 24, g4 = i - rr * 24;
    int gr = r0 + rr;
    if (gr >= 0 && gr < 96) {
      int gp = gr * 96 + g4 * 4;
      ushort4 p0 = *(const ushort4*)(op + gp);
      ushort4 p1 = *(const ushort4*)(op + HW + gp);
      ushort4 p2 = *(const ushort4*)(op + 2 * HW + gp);
      ushort4 p3 = *(const ushort4*)(op + (size_t)3 * HW + gp);
      float* dst = &lds[(rr * 100 + 2 + g4 * 4) * 4];
      *(float4*)(dst +  0) = make_float4(us2f(p0.x), us2f(p1.x), us2f(p2.x), us2f(p3.x));
      *(float4*)(dst +  4) = make_float4(us2f(p0.y), us2f(p1.y), us2f(p2.y), us2f(p3.y));
      *(float4*)(dst +  8) = make_float4(us2f(p0.z), us2f(p1.z), us2f(p2.z), us2f(p3.z));
      *(float4*)(dst + 12) = make_float4(us2f(p0.w), us2f(p1.w), us2f(p2.w), us2f(p3.w));
    }
  }
  __syncthreads();
  const float* wrow = wf + c * 36;
  float bias = bfu[c];
  float* outp = out + (size_t)(b * CC + c) * HW + tile * 24 * 96;
#pragma unroll
  for (int pi = 0; pi < 9; ++pi) {
    int p = pi * 256 + tid;
    int ry = p / 96, x = p - ry * 96;
    float a0 = bias, a1 = 0.f, a2 = 0.f, a3 = 0.f;
#pragma unroll
    for (int ky = 0; ky < 3; ++ky)
#pragma unroll
      for (int kx = 0; kx < 3; ++kx) {
        const float4 vv = *(const float4*)&lds[((ry + ky) * 100 + 1 + x + kx) * 4];
        a0 = fmaf(wrow[0 + ky * 3 + kx],  vv.x, a0);
        a1 = fmaf(wrow[9 + ky * 3 + kx],  vv.y, a1);
        a2 = fmaf(wrow[18 + ky * 3 + kx], vv.z, a2);
        a3 = fmaf(wrow[27 + ky * 3 + kx], vv.w, a3);
      }
    outp[p] = (a0 + a1) + (a2 + a3);
  }
}

// ---------------------------------------------------------------- launcher
extern "C" void kernel_launch(void* const* d_in, const int* in_sizes, int n_in,
                              void* d_out, int out_size, void* d_ws, size_t ws_size,
                              hipStream_t stream) {
  (void)in_sizes; (void)n_in; (void)out_size; (void)ws_size;
  const float* x   = (const float*)d_in[0];
  const float* wq  = (const float*)d_in[1];
  const float* bq  = (const float*)d_in[2];
  const float* tt  = (const float*)d_in[3];
  const float* wf  = (const float*)d_in[4];
  const float* bfu = (const float*)d_in[5];

  // workspace layout (~245 MB)
  char* ws = (char*)d_ws;
  bf16*  qg    = (bf16*)(ws + 0);                 // 75497472 B, later aliased by og
  bf16*  kg    = (bf16*)(ws + 75497472);          // 75497472 B
  bf16*  vg    = (bf16*)(ws + 150994944);         // 75497472 B
  float* part  = (float*)(ws + 226492416);        // 16777216 B
  bf16*  ah    = (bf16*)(ws + 243269632);         // 524288 B
  bf16*  al    = (bf16*)(ws + 243793920);         // 524288 B
  float* qn2   = (float*)(ws + 244318208);        // 16384 B
  float* kn2   = (float*)(ws + 244334592);        // 16384 B
  bf16*  og    = qg;                              // q is dead after k2_gram
  float* out   = (float*)d_out;

  hipLaunchKernelGGL(k1_qkv, dim3(1024), dim3(256), 0, stream,
                     x, wq, bq, qg, kg, vg, qn2, kn2);
  hipLaunchKernelGGL(k2_gram, dim3(NCH, 64), dim3(256), 0, stream, qg, kg, part);
  hipLaunchKernelGGL(k2_softmax, dim3(64, 4), dim3(256), 0, stream,
                     part, ah, al, qn2, kn2, tt);
  hipLaunchKernelGGL(k3_av, dim3(36, 64), dim3(256), 0, stream, ah, al, vg, og);
  hipLaunchKernelGGL(k4_fuse, dim3(4, 1024), dim3(256), 0, stream, og, wf, bfu, out);
}

// Round 9
// 245.031 us; speedup vs baseline: 1.0461x; 1.0461x over previous
//
#include <hip/hip_runtime.h>
#include <hip/hip_bf16.h>
#include <stdint.h>

// Problem constants
#define BB     8
#define CC     128
#define HW     9216      // 96*96
#define NHEAD  8
#define HD     64
#define NCH    16        // gram n-chunks
#define CHUNK  576       // HW/NCH
#define KPAD   68        // LDS row pad (px): 136B stride, 8B-aligned rows

typedef __hip_bfloat16 bf16;
using frag16 = __attribute__((ext_vector_type(8))) short;  // 8 bf16 (4 VGPRs)
using f32x4  = __attribute__((ext_vector_type(4))) float;

__device__ __forceinline__ float b2f(bf16 v) { return __bfloat162float(v); }
__device__ __forceinline__ bf16  f2b(float v) { return __float2bfloat16(v); }

__device__ __forceinline__ float us2f(unsigned short u) {
  union { unsigned int i; float f; } c; c.i = ((unsigned int)u) << 16; return c.f;
}

__device__ __forceinline__ unsigned int pack2(float a, float b) {
  union { __hip_bfloat162 h2; unsigned int u; } c;
  c.h2 = __float22bfloat162_rn(make_float2(a, b));   // v_cvt_pk_bf16_f32
  return c.u;
}

// LDS frag read from 8B-aligned address (rows are 136B-strided)
__device__ __forceinline__ frag16 ldsfrag(const unsigned short* p) {
  uint2 lo = *(const uint2*)p;
  uint2 hi = *(const uint2*)(p + 4);
  union { unsigned int u[4]; frag16 f; } c;
  c.u[0] = lo.x; c.u[1] = lo.y; c.u[2] = hi.x; c.u[3] = hi.y;
  return c.f;
}
// LDS 16B store as two 8B stores (8B-aligned dst)
__device__ __forceinline__ void ldsst(unsigned short* p, uint4 v) {
  *(uint2*)p = make_uint2(v.x, v.y);
  *(uint2*)(p + 4) = make_uint2(v.z, v.w);
}

// Shared staging for k1: zero-pad halo only (interior fully overwritten), then stage plane.
__device__ __forceinline__ void stage_plane(float* xs, const float* xp, int tid) {
  const float4 z4 = make_float4(0.f, 0.f, 0.f, 0.f);
  for (int i = tid; i < 98; i += 256) *(float4*)&xs[i * 100] = z4;        // cols 0..3
  for (int i = tid; i < 24; i += 256) *(float4*)&xs[4 + i * 4] = z4;     // row 0
  for (int i = tid; i < 25; i += 256) *(float4*)&xs[9704 + i * 4] = z4;  // row 97 + guard
  for (int i = tid; i < 96 * 24; i += 256) {
    int y = i / 24, g4 = i - y * 24;
    ((float4*)(xs + (y + 1) * 100 + 4))[g4] = ((const float4*)(xp + y * 96))[g4];
  }
}

// ---------------------------------------------------------------- K1: qkv depthwise conv + q/k norms
// block = (b, c), full 96x96 plane in LDS (R7 version, measured ~55us at grid 1024).
// Launched as TWO half-batch dispatches (b_base 0/4) so each lands ~28us -> drops the
// rocprof top-5 cutoff below the hidden kernels (observability, negligible cost).
__global__ __launch_bounds__(256) void k1_qkv(
    const float* __restrict__ x, const float* __restrict__ wq,
    const float* __restrict__ bq,
    bf16* __restrict__ qg, bf16* __restrict__ kg, bf16* __restrict__ vg,
    float* __restrict__ qn2, float* __restrict__ kn2, int b_base) {
  __shared__ float xs[98 * 100 + 4];
  __shared__ float red[32];
  int tid = threadIdx.x;
  int wave = tid >> 6, lane = tid & 63;
  int b = b_base + (blockIdx.x >> 7), c = blockIdx.x & 127;
  const float* xp = x + (size_t)(b * CC + c) * HW;
  stage_plane(xs, xp, tid);
  __syncthreads();

  int half = c >> 6, d = c & 63;
  int nidx[8];
  size_t basep[12];
#pragma unroll
  for (int j = 0; j < 12; ++j) {
    int e = j & 3;
    int h = e * 2 + half;
    int ni = (b * NHEAD + h) * HD + d;
    if (j < 8) nidx[j] = ni;
    basep[j] = (size_t)ni * HW;
  }
  const float* wrow = wq + c * 108;
  const float* brow = bq + c * 12;

  float ssq[8];
#pragma unroll
  for (int j = 0; j < 8; ++j) ssq[j] = 0.f;

#pragma unroll 1
  for (int it = 0; it < 5; ++it) {
    int u = it * 256 + tid;
    if (u < 1152) {
      int ly = u / 12;
      int x8 = (u - ly * 12) * 8;
      int p0 = ly * 96 + x8;
      float w10[3][10];
#pragma unroll
      for (int ky = 0; ky < 3; ++ky) {
        int basea = (ly + ky) * 100 + 4 + x8;
        float4 M0 = *(const float4*)&xs[basea];
        float4 M1 = *(const float4*)&xs[basea + 4];
        w10[ky][0] = xs[basea - 1];
        w10[ky][1] = M0.x; w10[ky][2] = M0.y; w10[ky][3] = M0.z; w10[ky][4] = M0.w;
        w10[ky][5] = M1.x; w10[ky][6] = M1.y; w10[ky][7] = M1.z; w10[ky][8] = M1.w;
        w10[ky][9] = xs[basea + 8];
      }
#pragma unroll
      for (int j = 0; j < 12; ++j) {
        float bias = brow[j];
        float a[8];
#pragma unroll
        for (int p = 0; p < 8; ++p) a[p] = bias;
#pragma unroll
        for (int ky = 0; ky < 3; ++ky)
#pragma unroll
          for (int kx = 0; kx < 3; ++kx) {
            float w = wrow[j * 9 + ky * 3 + kx];
#pragma unroll
            for (int p = 0; p < 8; ++p)
              a[p] = fmaf(w, w10[ky][kx + p], a[p]);
          }
        uint4 st;
        st.x = pack2(a[0], a[1]); st.y = pack2(a[2], a[3]);
        st.z = pack2(a[4], a[5]); st.w = pack2(a[6], a[7]);
        if (j < 4)      *(uint4*)(qg + basep[j] + p0) = st;
        else if (j < 8) *(uint4*)(kg + basep[j] + p0) = st;
        else            *(uint4*)(vg + basep[j] + p0) = st;
        if (j < 8) {
          float s2 = 0.f;
#pragma unroll
          for (int p = 0; p < 8; ++p) s2 = fmaf(a[p], a[p], s2);
          ssq[j] += s2;
        }
      }
    }
  }
#pragma unroll
  for (int j = 0; j < 8; ++j) {
    float v = ssq[j];
#pragma unroll
    for (int off = 32; off > 0; off >>= 1) v += __shfl_down(v, off);
    if (lane == 0) red[wave * 8 + j] = v;
  }
  __syncthreads();
  if (tid < 8) {
    float s = red[tid] + red[8 + tid] + red[16 + tid] + red[24 + tid];
    if (tid < 4) qn2[nidx[tid]] = s;
    else         kn2[nidx[tid]] = s;
  }
}

// ---------------------------------------------------------------- K2a: gram partials via MFMA, LDS-staged
// block = (chunk, bh). Per BK=64 step: stage q[64][64] + k[64][64] into padded LDS
// (coalesced 8-row x 128B bursts, k shared by all 4 waves), double-buffered,
// reg-staged (issue loads -> compute -> ds_write -> barrier).
__global__ __launch_bounds__(256) void k2_gram(
    const bf16* __restrict__ qg, const bf16* __restrict__ kg,
    float* __restrict__ part) {
  __shared__ unsigned short sq[2][64 * KPAD];   // 17408 B
  __shared__ unsigned short sk[2][64 * KPAD];   // 17408 B
  int tid = threadIdx.x;
  int wave = tid >> 6;           // 0..3 -> d-tile
  int lane = tid & 63;
  int chunk = blockIdx.x;        // 0..15
  int bh = blockIdx.y;           // 0..63
  const size_t base = (size_t)bh * HD * HW;
  int n0 = chunk * CHUNK;

  // staging coords: thread covers (row, seg16B) and (row+32, seg16B)
  int srow = tid >> 3;           // 0..31
  int sseg = tid & 7;            // 0..7 (8px each)
  const bf16* qs0 = qg + base + (size_t)srow * HW + n0 + sseg * 8;
  const bf16* qs1 = qs0 + (size_t)32 * HW;
  const bf16* ks0 = kg + base + (size_t)srow * HW + n0 + sseg * 8;
  const bf16* ks1 = ks0 + (size_t)32 * HW;
  int d0 = srow * KPAD + sseg * 8;
  int d1 = (srow + 32) * KPAD + sseg * 8;

  int m = lane & 15;
  int k8 = lane >> 4;            // 0..3
  int arow = wave * 16 + m;

  f32x4 acc0 = {0.f, 0.f, 0.f, 0.f}, acc1 = acc0, acc2 = acc0, acc3 = acc0;

  // prologue: stage step 0
  uint4 rq0 = *(const uint4*)(qs0);
  uint4 rq1 = *(const uint4*)(qs1);
  uint4 rk0 = *(const uint4*)(ks0);
  uint4 rk1 = *(const uint4*)(ks1);
  ldsst(&sq[0][d0], rq0); ldsst(&sq[0][d1], rq1);
  ldsst(&sk[0][d0], rk0); ldsst(&sk[0][d1], rk1);
  __syncthreads();

#pragma unroll 1
  for (int s = 0; s < 9; ++s) {
    if (s < 8) {                       // issue next-step loads early (T14)
      int off = (s + 1) * 64;
      rq0 = *(const uint4*)(qs0 + off);
      rq1 = *(const uint4*)(qs1 + off);
      rk0 = *(const uint4*)(ks0 + off);
      rk1 = *(const uint4*)(ks1 + off);
    }
    const unsigned short* sqc = sq[s & 1];
    const unsigned short* skc = sk[s & 1];
#pragma unroll
    for (int kk = 0; kk < 2; ++kk) {
      int co = kk * 32 + k8 * 8;
      frag16 a  = ldsfrag(&sqc[arow * KPAD + co]);
      frag16 b0 = ldsfrag(&skc[(m +  0) * KPAD + co]);
      frag16 b1 = ldsfrag(&skc[(m + 16) * KPAD + co]);
      frag16 b2 = ldsfrag(&skc[(m + 32) * KPAD + co]);
      frag16 b3 = ldsfrag(&skc[(m + 48) * KPAD + co]);
      acc0 = __builtin_amdgcn_mfma_f32_16x16x32_bf16(a, b0, acc0, 0, 0, 0);
      acc1 = __builtin_amdgcn_mfma_f32_16x16x32_bf16(a, b1, acc1, 0, 0, 0);
      acc2 = __builtin_amdgcn_mfma_f32_16x16x32_bf16(a, b2, acc2, 0, 0, 0);
      acc3 = __builtin_amdgcn_mfma_f32_16x16x32_bf16(a, b3, acc3, 0, 0, 0);
    }
    if (s < 8) {                       // write next buffer; single barrier per step
      int nb = (s + 1) & 1;
      ldsst(&sq[nb][d0], rq0); ldsst(&sq[nb][d1], rq1);
      ldsst(&sk[nb][d0], rk0); ldsst(&sk[nb][d1], rk1);
      __syncthreads();
    }
  }

  // C/D layout: row(d) = (lane>>4)*4 + r, col(e) = lane&15
  float* po = part + (size_t)(bh * NCH + chunk) * 4096;
  int dr = wave * 16 + (lane >> 4) * 4;
  int e0 = lane & 15;
#pragma unroll
  for (int r = 0; r < 4; ++r) {
    po[(dr + r) * 64 +  0 + e0] = acc0[r];
    po[(dr + r) * 64 + 16 + e0] = acc1[r];
    po[(dr + r) * 64 + 32 + e0] = acc2[r];
    po[(dr + r) * 64 + 48 + e0] = acc3[r];
  }
}

// ---------------------------------------------------------------- K2b: reduce partials + normalize + softmax
__global__ __launch_bounds__(256) void k2_softmax(
    const float* __restrict__ part, bf16* __restrict__ ah, bf16* __restrict__ al,
    const float* __restrict__ qn2, const float* __restrict__ kn2,
    const float* __restrict__ t_f) {
  __shared__ float kns[64];
  int bh = blockIdx.x;
  int dq = blockIdx.y;
  int tid = threadIdx.x;
  if (tid < 64) kns[tid] = fmaxf(sqrtf(kn2[bh * 64 + tid]), 1e-12f);
  __syncthreads();
  int d  = dq * 16 + (tid >> 4);
  int e0 = (tid & 15) * 4;

  const float* pb = part + (size_t)bh * NCH * 4096 + d * 64 + e0;
  float4 s = make_float4(0.f, 0.f, 0.f, 0.f);
#pragma unroll
  for (int ch = 0; ch < NCH; ++ch) {
    float4 g = *(const float4*)&pb[ch * 4096];
    s.x += g.x; s.y += g.y; s.z += g.z; s.w += g.w;
  }
  float v[4] = {s.x, s.y, s.z, s.w};
  float sc = t_f[bh & 7] / fmaxf(sqrtf(qn2[bh * 64 + d]), 1e-12f);
  float m = -1e30f;
#pragma unroll
  for (int j = 0; j < 4; ++j) {
    v[j] = v[j] * sc / kns[e0 + j];
    m = fmaxf(m, v[j]);
  }
  m = fmaxf(m, __shfl_xor(m, 1));
  m = fmaxf(m, __shfl_xor(m, 2));
  m = fmaxf(m, __shfl_xor(m, 4));
  m = fmaxf(m, __shfl_xor(m, 8));
  float ssum = 0.f;
#pragma unroll
  for (int j = 0; j < 4; ++j) { v[j] = __expf(v[j] - m); ssum += v[j]; }
  ssum += __shfl_xor(ssum, 1);
  ssum += __shfl_xor(ssum, 2);
  ssum += __shfl_xor(ssum, 4);
  ssum += __shfl_xor(ssum, 8);
  float inv = 1.f / ssum;
  unsigned short hi16[4], lo16[4];
#pragma unroll
  for (int j = 0; j < 4; ++j) {
    float p = v[j] * inv;
    bf16 hi = f2b(p);
    float lo = p - b2f(hi);
    bf16 lov = f2b(lo);
    hi16[j] = *(unsigned short*)&hi;
    lo16[j] = *(unsigned short*)&lov;
  }
  const size_t base = (size_t)bh * 4096 + d * 64 + e0;
  *(ushort4*)(ah + base) = *(ushort4*)&hi16[0];
  *(ushort4*)(al + base) = *(ushort4*)&lo16[0];
}

// ---------------------------------------------------------------- K3: o = attn @ v via MFMA
__global__ __launch_bounds__(256) void k3_av(
    const bf16* __restrict__ ah, const bf16* __restrict__ al,
    const bf16* __restrict__ vg, bf16* __restrict__ og) {
  int tid = threadIdx.x;
  int wave = tid >> 6, lane = tid & 63;
  int chunk = blockIdx.x;   // 0..35 (256 pixels each)
  int bh = blockIdx.y;      // 0..63
  int b = bh >> 3, h = bh & 7;
  int n0 = chunk * 256;
  int m = lane & 15;
  int k8 = (lane >> 4) * 8;
  int nwbase = wave * 64;

  const bf16* ahp = ah + (size_t)bh * 4096;
  const bf16* alp = al + (size_t)bh * 4096;
  frag16 a_hi[4][2], a_lo[4][2];
#pragma unroll
  for (int dt = 0; dt < 4; ++dt)
#pragma unroll
    for (int kh = 0; kh < 2; ++kh) {
      a_hi[dt][kh] = *(const frag16*)(ahp + (dt * 16 + m) * 64 + kh * 32 + k8);
      a_lo[dt][kh] = *(const frag16*)(alp + (dt * 16 + m) * 64 + kh * 32 + k8);
    }

  const bf16* vb = vg + (size_t)bh * HD * HW + n0 + nwbase + m;
  frag16 bfr[4][2];
#pragma unroll
  for (int kh = 0; kh < 2; ++kh)
#pragma unroll
    for (int j = 0; j < 8; ++j) {
      const bf16* vp = vb + (size_t)(kh * 32 + k8 + j) * HW;
      bfr[0][kh][j] = *(const short*)(vp);
      bfr[1][kh][j] = *(const short*)(vp + 16);
      bfr[2][kh][j] = *(const short*)(vp + 32);
      bfr[3][kh][j] = *(const short*)(vp + 48);
    }

  f32x4 acc[4][4];
#pragma unroll
  for (int dt = 0; dt < 4; ++dt)
#pragma unroll
    for (int nt = 0; nt < 4; ++nt) acc[dt][nt] = {0.f, 0.f, 0.f, 0.f};

#pragma unroll
  for (int nt = 0; nt < 4; ++nt)
#pragma unroll
    for (int kh = 0; kh < 2; ++kh)
#pragma unroll
      for (int dt = 0; dt < 4; ++dt) {
        acc[dt][nt] = __builtin_amdgcn_mfma_f32_16x16x32_bf16(a_hi[dt][kh], bfr[nt][kh], acc[dt][nt], 0, 0, 0);
        acc[dt][nt] = __builtin_amdgcn_mfma_f32_16x16x32_bf16(a_lo[dt][kh], bfr[nt][kh], acc[dt][nt], 0, 0, 0);
      }

  int cc0 = (h & 1) * 256 + (h >> 1);
  bf16* ob = og + (size_t)b * 512 * HW;
  int q4 = (lane >> 4) * 4;
#pragma unroll
  for (int dt = 0; dt < 4; ++dt)
#pragma unroll
    for (int nt = 0; nt < 4; ++nt) {
      int n = n0 + nwbase + nt * 16 + m;
#pragma unroll
      for (int r = 0; r < 4; ++r) {
        int d = dt * 16 + q4 + r;
        ob[(size_t)(cc0 + d * 4) * HW + n] = f2b(acc[dt][nt][r]);
      }
    }
}

// ---------------------------------------------------------------- K4: fused grouped 3x3 conv (4 in-ch -> 1 out-ch)
__global__ __launch_bounds__(256) void k4_fuse(
    const bf16* __restrict__ og, const float* __restrict__ wf,
    const float* __restrict__ bfu, float* __restrict__ out) {
  __shared__ float lds[26 * 100 * 4];   // 41.6 KB
  int tid = threadIdx.x;
  int tile = blockIdx.x;                // 0..3
  int bc = blockIdx.y;                  // 0..1023
  int b = bc >> 7, c = bc & 127;
  int r0 = tile * 24 - 1;
  const float4 z4 = make_float4(0.f, 0.f, 0.f, 0.f);
  for (int i = tid; i < 52; i += 256) {
    int rr = i >> 1, cc = (i & 1) ? 98 : 1;
    *(float4*)&lds[(rr * 100 + cc) * 4] = z4;
  }
  if (r0 < 0)
    for (int i = tid; i < 96; i += 256) *(float4*)&lds[(0 * 100 + 2 + i) * 4] = z4;
  if (r0 + 25 >= 96)
    for (int i = tid; i < 96; i += 256) *(float4*)&lds[(25 * 100 + 2 + i) * 4] = z4;
  const bf16* op = og + (size_t)(b * 512 + c * 4) * HW;
  for (int i = tid; i < 26 * 24; i += 256) {
    int rr = i / 24, g4 = i - rr * 24;
    int gr = r0 + rr;
    if (gr >= 0 && gr < 96) {
      int gp = gr * 96 + g4 * 4;
      ushort4 p0 = *(const ushort4*)(op + gp);
      ushort4 p1 = *(const ushort4*)(op + HW + gp);
      ushort4 p2 = *(const ushort4*)(op + 2 * HW + gp);
      ushort4 p3 = *(const ushort4*)(op + (size_t)3 * HW + gp);
      float* dst = &lds[(rr * 100 + 2 + g4 * 4) * 4];
      *(float4*)(dst +  0) = make_float4(us2f(p0.x), us2f(p1.x), us2f(p2.x), us2f(p3.x));
      *(float4*)(dst +  4) = make_float4(us2f(p0.y), us2f(p1.y), us2f(p2.y), us2f(p3.y));
      *(float4*)(dst +  8) = make_float4(us2f(p0.z), us2f(p1.z), us2f(p2.z), us2f(p3.z));
      *(float4*)(dst + 12) = make_float4(us2f(p0.w), us2f(p1.w), us2f(p2.w), us2f(p3.w));
    }
  }
  __syncthreads();
  const float* wrow = wf + c * 36;
  float bias = bfu[c];
  float* outp = out + (size_t)(b * CC + c) * HW + tile * 24 * 96;
#pragma unroll
  for (int pi = 0; pi < 9; ++pi) {
    int p = pi * 256 + tid;
    int ry = p / 96, x = p - ry * 96;
    float a0 = bias, a1 = 0.f, a2 = 0.f, a3 = 0.f;
#pragma unroll
    for (int ky = 0; ky < 3; ++ky)
#pragma unroll
      for (int kx = 0; kx < 3; ++kx) {
        const float4 vv = *(const float4*)&lds[((ry + ky) * 100 + 1 + x + kx) * 4];
        a0 = fmaf(wrow[0 + ky * 3 + kx],  vv.x, a0);
        a1 = fmaf(wrow[9 + ky * 3 + kx],  vv.y, a1);
        a2 = fmaf(wrow[18 + ky * 3 + kx], vv.z, a2);
        a3 = fmaf(wrow[27 + ky * 3 + kx], vv.w, a3);
      }
    outp[p] = (a0 + a1) + (a2 + a3);
  }
}

// ---------------------------------------------------------------- launcher
extern "C" void kernel_launch(void* const* d_in, const int* in_sizes, int n_in,
                              void* d_out, int out_size, void* d_ws, size_t ws_size,
                              hipStream_t stream) {
  (void)in_sizes; (void)n_in; (void)out_size; (void)ws_size;
  const float* x   = (const float*)d_in[0];
  const float* wq  = (const float*)d_in[1];
  const float* bq  = (const float*)d_in[2];
  const float* tt  = (const float*)d_in[3];
  const float* wf  = (const float*)d_in[4];
  const float* bfu = (const float*)d_in[5];

  // workspace layout (~245 MB)
  char* ws = (char*)d_ws;
  bf16*  qg    = (bf16*)(ws + 0);                 // 75497472 B, later aliased by og
  bf16*  kg    = (bf16*)(ws + 75497472);          // 75497472 B
  bf16*  vg    = (bf16*)(ws + 150994944);         // 75497472 B
  float* part  = (float*)(ws + 226492416);        // 16777216 B
  bf16*  ah    = (bf16*)(ws + 243269632);         // 524288 B
  bf16*  al    = (bf16*)(ws + 243793920);         // 524288 B
  float* qn2   = (float*)(ws + 244318208);        // 16384 B
  float* kn2   = (float*)(ws + 244334592);        // 16384 B
  bf16*  og    = qg;                              // q is dead after k2_gram
  float* out   = (float*)d_out;

  // k1 split into two half-batch dispatches (observability: drops top-5 cutoff
  // below the hidden kernels; same total work).
  hipLaunchKernelGGL(k1_qkv, dim3(512), dim3(256), 0, stream,
                     x, wq, bq, qg, kg, vg, qn2, kn2, 0);
  hipLaunchKernelGGL(k1_qkv, dim3(512), dim3(256), 0, stream,
                     x, wq, bq, qg, kg, vg, qn2, kn2, 4);
  hipLaunchKernelGGL(k2_gram, dim3(NCH, 64), dim3(256), 0, stream, qg, kg, part);
  hipLaunchKernelGGL(k2_softmax, dim3(64, 4), dim3(256), 0, stream,
                     part, ah, al, qn2, kn2, tt);
  hipLaunchKernelGGL(k3_av, dim3(36, 64), dim3(256), 0, stream, ah, al, vg, og);
  hipLaunchKernelGGL(k4_fuse, dim3(4, 1024), dim3(256), 0, stream, og, wf, bfu, out);
}

// Round 11
// 226.363 us; speedup vs baseline: 1.1324x; 1.0825x over previous
//
#include <hip/hip_runtime.h>
#include <hip/hip_bf16.h>
#include <stdint.h>

// Problem constants
#define BB     8
#define CC     128
#define HW     9216      // 96*96
#define NHEAD  8
#define HD     64
#define NCH    16        // gram n-chunks
#define CHUNK  576       // HW/NCH
#define KPAD   68        // LDS row pad (px): 136B stride, 8B-aligned rows

typedef __hip_bfloat16 bf16;
using frag16 = __attribute__((ext_vector_type(8))) short;  // 8 bf16 (4 VGPRs)
using f32x4  = __attribute__((ext_vector_type(4))) float;

__device__ __forceinline__ float b2f(bf16 v) { return __bfloat162float(v); }
__device__ __forceinline__ bf16  f2b(float v) { return __float2bfloat16(v); }

__device__ __forceinline__ float lo2f(unsigned int u) {
  union { unsigned int i; float f; } c; c.i = u << 16; return c.f;
}
__device__ __forceinline__ float hi2f(unsigned int u) {
  union { unsigned int i; float f; } c; c.i = u & 0xffff0000u; return c.f;
}

__device__ __forceinline__ unsigned int pack2(float a, float b) {
  union { __hip_bfloat162 h2; unsigned int u; } c;
  c.h2 = __float22bfloat162_rn(make_float2(a, b));   // v_cvt_pk_bf16_f32
  return c.u;
}

// LDS frag read from 8B-aligned address (rows are 136B-strided)
__device__ __forceinline__ frag16 ldsfrag(const unsigned short* p) {
  uint2 lo = *(const uint2*)p;
  uint2 hi = *(const uint2*)(p + 4);
  union { unsigned int u[4]; frag16 f; } c;
  c.u[0] = lo.x; c.u[1] = lo.y; c.u[2] = hi.x; c.u[3] = hi.y;
  return c.f;
}
// LDS 16B store as two 8B stores (8B-aligned dst)
__device__ __forceinline__ void ldsst(unsigned short* p, uint4 v) {
  *(uint2*)p = make_uint2(v.x, v.y);
  *(uint2*)(p + 4) = make_uint2(v.z, v.w);
}

// Shared staging for k1: zero-pad halo only (interior fully overwritten), then stage plane.
__device__ __forceinline__ void stage_plane(float* xs, const float* xp, int tid) {
  const float4 z4 = make_float4(0.f, 0.f, 0.f, 0.f);
  for (int i = tid; i < 98; i += 256) *(float4*)&xs[i * 100] = z4;        // cols 0..3
  for (int i = tid; i < 24; i += 256) *(float4*)&xs[4 + i * 4] = z4;     // row 0
  for (int i = tid; i < 25; i += 256) *(float4*)&xs[9704 + i * 4] = z4;  // row 97 + guard
  for (int i = tid; i < 96 * 24; i += 256) {
    int y = i / 24, g4 = i - y * 24;
    ((float4*)(xs + (y + 1) * 100 + 4))[g4] = ((const float4*)(xp + y * 96))[g4];
  }
}

// ---------------------------------------------------------------- K1: qkv depthwise conv + q/k norms
// block = (b, c), full 96x96 plane in LDS (R7 version, ~55us), single dispatch.
__global__ __launch_bounds__(256) void k1_qkv(
    const float* __restrict__ x, const float* __restrict__ wq,
    const float* __restrict__ bq,
    bf16* __restrict__ qg, bf16* __restrict__ kg, bf16* __restrict__ vg,
    float* __restrict__ qn2, float* __restrict__ kn2) {
  __shared__ float xs[98 * 100 + 4];
  __shared__ float red[32];
  int tid = threadIdx.x;
  int wave = tid >> 6, lane = tid & 63;
  int b = blockIdx.x >> 7, c = blockIdx.x & 127;
  const float* xp = x + (size_t)(b * CC + c) * HW;
  stage_plane(xs, xp, tid);
  __syncthreads();

  int half = c >> 6, d = c & 63;
  int nidx[8];
  size_t basep[12];
#pragma unroll
  for (int j = 0; j < 12; ++j) {
    int e = j & 3;
    int h = e * 2 + half;
    int ni = (b * NHEAD + h) * HD + d;
    if (j < 8) nidx[j] = ni;
    basep[j] = (size_t)ni * HW;
  }
  const float* wrow = wq + c * 108;
  const float* brow = bq + c * 12;

  float ssq[8];
#pragma unroll
  for (int j = 0; j < 8; ++j) ssq[j] = 0.f;

#pragma unroll 1
  for (int it = 0; it < 5; ++it) {
    int u = it * 256 + tid;
    if (u < 1152) {
      int ly = u / 12;
      int x8 = (u - ly * 12) * 8;
      int p0 = ly * 96 + x8;
      float w10[3][10];
#pragma unroll
      for (int ky = 0; ky < 3; ++ky) {
        int basea = (ly + ky) * 100 + 4 + x8;
        float4 M0 = *(const float4*)&xs[basea];
        float4 M1 = *(const float4*)&xs[basea + 4];
        w10[ky][0] = xs[basea - 1];
        w10[ky][1] = M0.x; w10[ky][2] = M0.y; w10[ky][3] = M0.z; w10[ky][4] = M0.w;
        w10[ky][5] = M1.x; w10[ky][6] = M1.y; w10[ky][7] = M1.z; w10[ky][8] = M1.w;
        w10[ky][9] = xs[basea + 8];
      }
#pragma unroll
      for (int j = 0; j < 12; ++j) {
        float bias = brow[j];
        float a[8];
#pragma unroll
        for (int p = 0; p < 8; ++p) a[p] = bias;
#pragma unroll
        for (int ky = 0; ky < 3; ++ky)
#pragma unroll
          for (int kx = 0; kx < 3; ++kx) {
            float w = wrow[j * 9 + ky * 3 + kx];
#pragma unroll
            for (int p = 0; p < 8; ++p)
              a[p] = fmaf(w, w10[ky][kx + p], a[p]);
          }
        uint4 st;
        st.x = pack2(a[0], a[1]); st.y = pack2(a[2], a[3]);
        st.z = pack2(a[4], a[5]); st.w = pack2(a[6], a[7]);
        if (j < 4)      *(uint4*)(qg + basep[j] + p0) = st;
        else if (j < 8) *(uint4*)(kg + basep[j] + p0) = st;
        else            *(uint4*)(vg + basep[j] + p0) = st;
        if (j < 8) {
          float s2 = 0.f;
#pragma unroll
          for (int p = 0; p < 8; ++p) s2 = fmaf(a[p], a[p], s2);
          ssq[j] += s2;
        }
      }
    }
  }
#pragma unroll
  for (int j = 0; j < 8; ++j) {
    float v = ssq[j];
#pragma unroll
    for (int off = 32; off > 0; off >>= 1) v += __shfl_down(v, off);
    if (lane == 0) red[wave * 8 + j] = v;
  }
  __syncthreads();
  if (tid < 8) {
    float s = red[tid] + red[8 + tid] + red[16 + tid] + red[24 + tid];
    if (tid < 4) qn2[nidx[tid]] = s;
    else         kn2[nidx[tid]] = s;
  }
}

// ---------------------------------------------------------------- K2a: gram partials via MFMA, LDS-staged
__global__ __launch_bounds__(256) void k2_gram(
    const bf16* __restrict__ qg, const bf16* __restrict__ kg,
    float* __restrict__ part) {
  __shared__ unsigned short sq[2][64 * KPAD];   // 17408 B
  __shared__ unsigned short sk[2][64 * KPAD];   // 17408 B
  int tid = threadIdx.x;
  int wave = tid >> 6;           // 0..3 -> d-tile
  int lane = tid & 63;
  int chunk = blockIdx.x;        // 0..15
  int bh = blockIdx.y;           // 0..63
  const size_t base = (size_t)bh * HD * HW;
  int n0 = chunk * CHUNK;

  int srow = tid >> 3;           // 0..31
  int sseg = tid & 7;            // 0..7 (8px each)
  const bf16* qs0 = qg + base + (size_t)srow * HW + n0 + sseg * 8;
  const bf16* qs1 = qs0 + (size_t)32 * HW;
  const bf16* ks0 = kg + base + (size_t)srow * HW + n0 + sseg * 8;
  const bf16* ks1 = ks0 + (size_t)32 * HW;
  int d0 = srow * KPAD + sseg * 8;
  int d1 = (srow + 32) * KPAD + sseg * 8;

  int m = lane & 15;
  int k8 = lane >> 4;            // 0..3
  int arow = wave * 16 + m;

  f32x4 acc0 = {0.f, 0.f, 0.f, 0.f}, acc1 = acc0, acc2 = acc0, acc3 = acc0;

  uint4 rq0 = *(const uint4*)(qs0);
  uint4 rq1 = *(const uint4*)(qs1);
  uint4 rk0 = *(const uint4*)(ks0);
  uint4 rk1 = *(const uint4*)(ks1);
  ldsst(&sq[0][d0], rq0); ldsst(&sq[0][d1], rq1);
  ldsst(&sk[0][d0], rk0); ldsst(&sk[0][d1], rk1);
  __syncthreads();

#pragma unroll 1
  for (int s = 0; s < 9; ++s) {
    if (s < 8) {                       // issue next-step loads early (T14)
      int off = (s + 1) * 64;
      rq0 = *(const uint4*)(qs0 + off);
      rq1 = *(const uint4*)(qs1 + off);
      rk0 = *(const uint4*)(ks0 + off);
      rk1 = *(const uint4*)(ks1 + off);
    }
    const unsigned short* sqc = sq[s & 1];
    const unsigned short* skc = sk[s & 1];
#pragma unroll
    for (int kk = 0; kk < 2; ++kk) {
      int co = kk * 32 + k8 * 8;
      frag16 a  = ldsfrag(&sqc[arow * KPAD + co]);
      frag16 b0 = ldsfrag(&skc[(m +  0) * KPAD + co]);
      frag16 b1 = ldsfrag(&skc[(m + 16) * KPAD + co]);
      frag16 b2 = ldsfrag(&skc[(m + 32) * KPAD + co]);
      frag16 b3 = ldsfrag(&skc[(m + 48) * KPAD + co]);
      acc0 = __builtin_amdgcn_mfma_f32_16x16x32_bf16(a, b0, acc0, 0, 0, 0);
      acc1 = __builtin_amdgcn_mfma_f32_16x16x32_bf16(a, b1, acc1, 0, 0, 0);
      acc2 = __builtin_amdgcn_mfma_f32_16x16x32_bf16(a, b2, acc2, 0, 0, 0);
      acc3 = __builtin_amdgcn_mfma_f32_16x16x32_bf16(a, b3, acc3, 0, 0, 0);
    }
    if (s < 8) {
      int nb = (s + 1) & 1;
      ldsst(&sq[nb][d0], rq0); ldsst(&sq[nb][d1], rq1);
      ldsst(&sk[nb][d0], rk0); ldsst(&sk[nb][d1], rk1);
      __syncthreads();
    }
  }

  // C/D layout: row(d) = (lane>>4)*4 + r, col(e) = lane&15
  float* po = part + (size_t)(bh * NCH + chunk) * 4096;
  int dr = wave * 16 + (lane >> 4) * 4;
  int e0 = lane & 15;
#pragma unroll
  for (int r = 0; r < 4; ++r) {
    po[(dr + r) * 64 +  0 + e0] = acc0[r];
    po[(dr + r) * 64 + 16 + e0] = acc1[r];
    po[(dr + r) * 64 + 32 + e0] = acc2[r];
    po[(dr + r) * 64 + 48 + e0] = acc3[r];
  }
}

// ---------------------------------------------------------------- K2b: reduce partials + normalize + softmax
__global__ __launch_bounds__(256) void k2_softmax(
    const float* __restrict__ part, bf16* __restrict__ ah, bf16* __restrict__ al,
    const float* __restrict__ qn2, const float* __restrict__ kn2,
    const float* __restrict__ t_f) {
  __shared__ float kns[64];
  int bh = blockIdx.x;
  int dq = blockIdx.y;
  int tid = threadIdx.x;
  if (tid < 64) kns[tid] = fmaxf(sqrtf(kn2[bh * 64 + tid]), 1e-12f);
  __syncthreads();
  int d  = dq * 16 + (tid >> 4);
  int e0 = (tid & 15) * 4;

  const float* pb = part + (size_t)bh * NCH * 4096 + d * 64 + e0;
  float4 s = make_float4(0.f, 0.f, 0.f, 0.f);
#pragma unroll
  for (int ch = 0; ch < NCH; ++ch) {
    float4 g = *(const float4*)&pb[ch * 4096];
    s.x += g.x; s.y += g.y; s.z += g.z; s.w += g.w;
  }
  float v[4] = {s.x, s.y, s.z, s.w};
  float sc = t_f[bh & 7] / fmaxf(sqrtf(qn2[bh * 64 + d]), 1e-12f);
  float m = -1e30f;
#pragma unroll
  for (int j = 0; j < 4; ++j) {
    v[j] = v[j] * sc / kns[e0 + j];
    m = fmaxf(m, v[j]);
  }
  m = fmaxf(m, __shfl_xor(m, 1));
  m = fmaxf(m, __shfl_xor(m, 2));
  m = fmaxf(m, __shfl_xor(m, 4));
  m = fmaxf(m, __shfl_xor(m, 8));
  float ssum = 0.f;
#pragma unroll
  for (int j = 0; j < 4; ++j) { v[j] = __expf(v[j] - m); ssum += v[j]; }
  ssum += __shfl_xor(ssum, 1);
  ssum += __shfl_xor(ssum, 2);
  ssum += __shfl_xor(ssum, 4);
  ssum += __shfl_xor(ssum, 8);
  float inv = 1.f / ssum;
  unsigned short hi16[4], lo16[4];
#pragma unroll
  for (int j = 0; j < 4; ++j) {
    float p = v[j] * inv;
    bf16 hi = f2b(p);
    float lo = p - b2f(hi);
    bf16 lov = f2b(lo);
    hi16[j] = *(unsigned short*)&hi;
    lo16[j] = *(unsigned short*)&lov;
  }
  const size_t base = (size_t)bh * 4096 + d * 64 + e0;
  *(ushort4*)(ah + base) = *(ushort4*)&hi16[0];
  *(ushort4*)(al + base) = *(ushort4*)&lo16[0];
}

// ---------------------------------------------------------------- K3: o = attn @ v via MFMA
__global__ __launch_bounds__(256) void k3_av(
    const bf16* __restrict__ ah, const bf16* __restrict__ al,
    const bf16* __restrict__ vg, bf16* __restrict__ og) {
  int tid = threadIdx.x;
  int wave = tid >> 6, lane = tid & 63;
  int chunk = blockIdx.x;   // 0..35 (256 pixels each)
  int bh = blockIdx.y;      // 0..63
  int b = bh >> 3, h = bh & 7;
  int n0 = chunk * 256;
  int m = lane & 15;
  int k8 = (lane >> 4) * 8;
  int nwbase = wave * 64;

  const bf16* ahp = ah + (size_t)bh * 4096;
  const bf16* alp = al + (size_t)bh * 4096;
  frag16 a_hi[4][2], a_lo[4][2];
#pragma unroll
  for (int dt = 0; dt < 4; ++dt)
#pragma unroll
    for (int kh = 0; kh < 2; ++kh) {
      a_hi[dt][kh] = *(const frag16*)(ahp + (dt * 16 + m) * 64 + kh * 32 + k8);
      a_lo[dt][kh] = *(const frag16*)(alp + (dt * 16 + m) * 64 + kh * 32 + k8);
    }

  const bf16* vb = vg + (size_t)bh * HD * HW + n0 + nwbase + m;
  frag16 bfr[4][2];
#pragma unroll
  for (int kh = 0; kh < 2; ++kh)
#pragma unroll
    for (int j = 0; j < 8; ++j) {
      const bf16* vp = vb + (size_t)(kh * 32 + k8 + j) * HW;
      bfr[0][kh][j] = *(const short*)(vp);
      bfr[1][kh][j] = *(const short*)(vp + 16);
      bfr[2][kh][j] = *(const short*)(vp + 32);
      bfr[3][kh][j] = *(const short*)(vp + 48);
    }

  f32x4 acc[4][4];
#pragma unroll
  for (int dt = 0; dt < 4; ++dt)
#pragma unroll
    for (int nt = 0; nt < 4; ++nt) acc[dt][nt] = {0.f, 0.f, 0.f, 0.f};

#pragma unroll
  for (int nt = 0; nt < 4; ++nt)
#pragma unroll
    for (int kh = 0; kh < 2; ++kh)
#pragma unroll
      for (int dt = 0; dt < 4; ++dt) {
        acc[dt][nt] = __builtin_amdgcn_mfma_f32_16x16x32_bf16(a_hi[dt][kh], bfr[nt][kh], acc[dt][nt], 0, 0, 0);
        acc[dt][nt] = __builtin_amdgcn_mfma_f32_16x16x32_bf16(a_lo[dt][kh], bfr[nt][kh], acc[dt][nt], 0, 0, 0);
      }

  int cc0 = (h & 1) * 256 + (h >> 1);
  bf16* ob = og + (size_t)b * 512 * HW;
  int q4 = (lane >> 4) * 4;
#pragma unroll
  for (int dt = 0; dt < 4; ++dt)
#pragma unroll
    for (int nt = 0; nt < 4; ++nt) {
      int n = n0 + nwbase + nt * 16 + m;
#pragma unroll
      for (int r = 0; r < 4; ++r) {
        int d = dt * 16 + q4 + r;
        ob[(size_t)(cc0 + d * 4) * HW + n] = f2b(acc[dt][nt][r]);
      }
    }
}

// ---------------------------------------------------------------- K4: fused grouped 3x3 conv (4 in-ch -> 1 out-ch)
// bf16 channel-interleaved cells: ushort cells[26][100][4] = 20.8 KB (was 41.6 KB f32)
// -> 7 blocks/CU occupancy (was 3), LDS read bytes halved (b64/tap), staging writes
// conflict-free (uint4 per 2 cells, 16B lane stride). Converts bf16->f32 at tap read
// (2 shifts per channel-pair, VALU has slack at 25%).
__global__ __launch_bounds__(256) void k4_fuse(
    const bf16* __restrict__ og, const float* __restrict__ wf,
    const float* __restrict__ bfu, float* __restrict__ out) {
  __shared__ unsigned short cells[26 * 100 * 4];   // 20800 B
  int tid = threadIdx.x;
  int tile = blockIdx.x;                // 0..3
  int bc = blockIdx.y;                  // 0..1023
  int b = bc >> 7, c = bc & 127;
  int r0 = tile * 24 - 1;
  // halo cols 1 and 98 (8B cells)
  const uint2 z2 = make_uint2(0u, 0u);
  for (int i = tid; i < 52; i += 256) {
    int rr = i >> 1, cc = (i & 1) ? 98 : 1;
    *(uint2*)&cells[(rr * 100 + cc) * 4] = z2;
  }
  // out-of-range halo rows, cols 2..97 (pairs of cells = uint4)
  const uint4 z4 = make_uint4(0u, 0u, 0u, 0u);
  if (r0 < 0)
    for (int i = tid; i < 48; i += 256) *(uint4*)&cells[(0 * 100 + 2 + i * 2) * 4] = z4;
  if (r0 + 25 >= 96)
    for (int i = tid; i < 48; i += 256) *(uint4*)&cells[(25 * 100 + 2 + i * 2) * 4] = z4;
  const bf16* op = og + (size_t)(b * 512 + c * 4) * HW;
  // stage: unit = (row, px-pair); ushort2 per channel, transpose-pack, one uint4
  // write per 2 cells (16B lane stride -> conflict-free)
  for (int u = tid; u < 26 * 48; u += 256) {
    int rr = u / 48, pr = u - rr * 48;
    int gr = r0 + rr;
    if (gr >= 0 && gr < 96) {
      int gp = gr * 96 + pr * 2;
      unsigned int A = *(const unsigned int*)(op + gp);
      unsigned int B = *(const unsigned int*)(op + HW + gp);
      unsigned int C = *(const unsigned int*)(op + 2 * HW + gp);
      unsigned int D = *(const unsigned int*)(op + (size_t)3 * HW + gp);
      uint4 w;
      w.x = (A & 0xffffu) | (B << 16);          // px0: ch0|ch1
      w.y = (C & 0xffffu) | (D << 16);          // px0: ch2|ch3
      w.z = (A >> 16) | (B & 0xffff0000u);      // px1: ch0|ch1
      w.w = (C >> 16) | (D & 0xffff0000u);      // px1: ch2|ch3
      *(uint4*)&cells[(rr * 100 + 2 + pr * 2) * 4] = w;
    }
  }
  __syncthreads();
  const float* wrow = wf + c * 36;      // uniform -> s_load
  float bias = bfu[c];
  float* outp = out + (size_t)(b * CC + c) * HW + tile * 24 * 96;
#pragma unroll
  for (int pi = 0; pi < 9; ++pi) {
    int p = pi * 256 + tid;
    int ry = p / 96, x = p - ry * 96;
    float a0 = bias, a1 = 0.f, a2 = 0.f, a3 = 0.f;
#pragma unroll
    for (int ky = 0; ky < 3; ++ky) {
      int basec = (ry + ky) * 100 + 1 + x;
#pragma unroll
      for (int kx = 0; kx < 3; ++kx) {
        uint2 cc2 = *(const uint2*)&cells[(basec + kx) * 4];   // b64, 2 lanes/bank
        a0 = fmaf(wrow[0 + ky * 3 + kx],  lo2f(cc2.x), a0);
        a1 = fmaf(wrow[9 + ky * 3 + kx],  hi2f(cc2.x), a1);
        a2 = fmaf(wrow[18 + ky * 3 + kx], lo2f(cc2.y), a2);
        a3 = fmaf(wrow[27 + ky * 3 + kx], hi2f(cc2.y), a3);
      }
    }
    outp[p] = (a0 + a1) + (a2 + a3);
  }
}

// ---------------------------------------------------------------- launcher
extern "C" void kernel_launch(void* const* d_in, const int* in_sizes, int n_in,
                              void* d_out, int out_size, void* d_ws, size_t ws_size,
                              hipStream_t stream) {
  (void)in_sizes; (void)n_in; (void)out_size; (void)ws_size;
  const float* x   = (const float*)d_in[0];
  const float* wq  = (const float*)d_in[1];
  const float* bq  = (const float*)d_in[2];
  const float* tt  = (const float*)d_in[3];
  const float* wf  = (const float*)d_in[4];
  const float* bfu = (const float*)d_in[5];

  // workspace layout (~245 MB)
  char* ws = (char*)d_ws;
  bf16*  qg    = (bf16*)(ws + 0);                 // 75497472 B, later aliased by og
  bf16*  kg    = (bf16*)(ws + 75497472);          // 75497472 B
  bf16*  vg    = (bf16*)(ws + 150994944);         // 75497472 B
  float* part  = (float*)(ws + 226492416);        // 16777216 B
  bf16*  ah    = (bf16*)(ws + 243269632);         // 524288 B
  bf16*  al    = (bf16*)(ws + 243793920);         // 524288 B
  float* qn2   = (float*)(ws + 244318208);        // 16384 B
  float* kn2   = (float*)(ws + 244334592);        // 16384 B
  bf16*  og    = qg;                              // q is dead after k2_gram
  float* out   = (float*)d_out;

  hipLaunchKernelGGL(k1_qkv, dim3(1024), dim3(256), 0, stream,
                     x, wq, bq, qg, kg, vg, qn2, kn2);
  hipLaunchKernelGGL(k2_gram, dim3(NCH, 64), dim3(256), 0, stream, qg, kg, part);
  hipLaunchKernelGGL(k2_softmax, dim3(64, 4), dim3(256), 0, stream,
                     part, ah, al, qn2, kn2, tt);
  hipLaunchKernelGGL(k3_av, dim3(36, 64), dim3(256), 0, stream, ah, al, vg, og);
  hipLaunchKernelGGL(k4_fuse, dim3(4, 1024), dim3(256), 0, stream, og, wf, bfu, out);
}